// Round 8
// baseline (31255.515 us; speedup 1.0000x reference)
//
#include <hip/hip_runtime.h>
#include <math.h>

#define SEQ   2048
#define BATCH 64
#define NIN   256
#define NHID  512
#define NOUT  128

// ---- workspace layout ----
// Primary: [Wq 1MB][hfin 128KB][xp 268.4MB]  (needs ~269.6 MB)
// Fallback (no room for Wq): [hfin][xp] and W_hh read row-major directly.
#define WQ_BYTES    ((size_t)NHID*NHID*4)            // 1 MB transposed W_hh
#define HFIN_BYTES  ((size_t)BATCH*NHID*4)           // 128 KB final hidden
#define XP_BYTES    ((size_t)SEQ*BATCH*NHID*4)       // 268.4 MB x-projection

typedef unsigned int u32;

// ---------------- W_hh transpose prep: Wq[kq][j] = Whh[j][4kq..4kq+3] -------
// One-time 1MB shuffle. Writes perfectly coalesced; reads uncoalesced but
// one-shot (L2 absorbs). 128 blocks x 512 threads, 1 float4/thread.
__global__ __launch_bounds__(512, 1)
void wq_prep_kernel(const float* __restrict__ Whh, float4* __restrict__ wq)
{
  const int kq = blockIdx.x;        // 0..127
  const int j  = threadIdx.x;       // 0..511
  wq[((size_t)kq << 9) + j] = *(const float4*)&Whh[(size_t)j*NHID + (kq << 2)];
}

// ---------------- x-projection GEMM (unchanged from r7, verified) -----------
// xp[row][j] = x[row,:]·Wih[j,:] + bih[j] + bhh[j];  row = t*64+b.
__global__ __launch_bounds__(256, 1)
void xproj_kernel(const float* __restrict__ x,
                  const float* __restrict__ Wih,
                  const float* __restrict__ bih,
                  const float* __restrict__ bhh,
                  float* __restrict__ xp)
{
  const int bj = blockIdx.x & 7;        // j-tile (64 j)
  const int bm = blockIdx.x >> 3;       // m-group (512 rows)
  const int tid = threadIdx.x;
  const int tx = tid & 15, ty = tid >> 4;

  __shared__ __align__(16) float  wT[NIN][68];   // [k][j] transposed
  __shared__ __align__(16) float4 xS[64][66];    // [m][kq] k-vectorized

  for (int it = 0; it < 64; ++it) {
    const int widx = tid + (it << 8);
    const int k = widx >> 6, j = widx & 63;
    wT[k][j] = Wih[(size_t)(bj*64 + j)*NIN + k];
  }
  const int jg = bj*64 + tx*4;
  float4 bv;
  bv.x = bih[jg+0]+bhh[jg+0]; bv.y = bih[jg+1]+bhh[jg+1];
  bv.z = bih[jg+2]+bhh[jg+2]; bv.w = bih[jg+3]+bhh[jg+3];
  __syncthreads();

  for (int mt = 0; mt < 8; ++mt) {
    const size_t r0 = (size_t)bm*512 + mt*64;
    for (int it = 0; it < 16; ++it) {
      const int f = tid + (it << 8);
      const int m = f >> 6, kq = f & 63;
      xS[m][kq] = *(const float4*)&x[(r0 + m)*NIN + (kq << 2)];
    }
    __syncthreads();

    float acc[4][4];
    #pragma unroll
    for (int q = 0; q < 4; ++q)
      #pragma unroll
      for (int jj = 0; jj < 4; ++jj) acc[q][jj] = 0.f;

    for (int kq = 0; kq < 64; ++kq) {
      const float4 xv0 = xS[ty*4+0][kq];
      const float4 xv1 = xS[ty*4+1][kq];
      const float4 xv2 = xS[ty*4+2][kq];
      const float4 xv3 = xS[ty*4+3][kq];
      #pragma unroll
      for (int i = 0; i < 4; ++i) {
        const float4 wv = *(const float4*)&wT[(kq<<2)+i][tx*4];
        const float xi0 = (i==0)?xv0.x:(i==1)?xv0.y:(i==2)?xv0.z:xv0.w;
        const float xi1 = (i==0)?xv1.x:(i==1)?xv1.y:(i==2)?xv1.z:xv1.w;
        const float xi2 = (i==0)?xv2.x:(i==1)?xv2.y:(i==2)?xv2.z:xv2.w;
        const float xi3 = (i==0)?xv3.x:(i==1)?xv3.y:(i==2)?xv3.z:xv3.w;
        acc[0][0]=fmaf(xi0,wv.x,acc[0][0]); acc[0][1]=fmaf(xi0,wv.y,acc[0][1]);
        acc[0][2]=fmaf(xi0,wv.z,acc[0][2]); acc[0][3]=fmaf(xi0,wv.w,acc[0][3]);
        acc[1][0]=fmaf(xi1,wv.x,acc[1][0]); acc[1][1]=fmaf(xi1,wv.y,acc[1][1]);
        acc[1][2]=fmaf(xi1,wv.z,acc[1][2]); acc[1][3]=fmaf(xi1,wv.w,acc[1][3]);
        acc[2][0]=fmaf(xi2,wv.x,acc[2][0]); acc[2][1]=fmaf(xi2,wv.y,acc[2][1]);
        acc[2][2]=fmaf(xi2,wv.z,acc[2][2]); acc[2][3]=fmaf(xi2,wv.w,acc[2][3]);
        acc[3][0]=fmaf(xi3,wv.x,acc[3][0]); acc[3][1]=fmaf(xi3,wv.y,acc[3][1]);
        acc[3][2]=fmaf(xi3,wv.z,acc[3][2]); acc[3][3]=fmaf(xi3,wv.w,acc[3][3]);
      }
    }
    #pragma unroll
    for (int q = 0; q < 4; ++q) {
      float4 o;
      o.x = acc[q][0]+bv.x; o.y = acc[q][1]+bv.y;
      o.z = acc[q][2]+bv.z; o.w = acc[q][3]+bv.w;
      *(float4*)&xp[(r0 + ty*4 + q)*NHID + jg] = o;
    }
    __syncthreads();
  }
}

// ---------------- batch-split recurrent kernel: ZERO inter-block comm -------
// 64 blocks x 512 threads: block = one batch row, thread = one hidden unit j.
// h ping-pongs in LDS (one __syncthreads per step). W_hh streams from L2:
//   WMODE 0: Wq[kq][j] transposed layout -> per-kq loads fully coalesced.
//   WMODE 1: direct row-major Whh[j][4kq..] (fallback, no Wq workspace).
// h read as ds_read_b128 broadcast (all lanes same addr -> conflict-free).
template<int WMODE>
__global__ __launch_bounds__(512, 2)
void rnn_seq_kernel(const float* __restrict__ xp,
                    const float* __restrict__ wsrc,   // Wq (0) or Whh (1)
                    float* __restrict__ hfin)
{
  const int b = blockIdx.x;     // 0..63 batch row
  const int j = threadIdx.x;    // 0..511 hidden unit

  __shared__ __align__(16) float hh[2][NHID];   // 4 KB ping-pong
  hh[0][j] = 0.f;                               // h(0) = 0

  const float4* wq   = (const float4*)wsrc;                 // WMODE 0
  const float*  wrow = wsrc + (size_t)j*NHID;               // WMODE 1
  const float*  xcol = xp + (size_t)b*NHID + j;             // xp[t][b][j]
  float xpC = xcol[0];
  float hnew = 0.f;
  __syncthreads();

  for (int t = 0; t < SEQ; ++t) {
    const int par = t & 1;
    // prefetch next step's xp (coalesced 4B/lane; full step to land)
    float xpN = 0.f;
    if (t + 1 < SEQ) xpN = xcol[(size_t)(t+1)*(BATCH*NHID)];

    const float* hA = hh[par];
    float a0=0.f, a1=0.f, a2=0.f, a3=0.f;
    #pragma unroll 8
    for (int kq = 0; kq < 128; ++kq) {
      float4 wv;
      if constexpr (WMODE == 0) wv = wq[(kq << 9) | j];
      else                      wv = *(const float4*)&wrow[kq << 2];
      const float4 hv = *(const float4*)&hA[kq << 2];   // LDS broadcast
      a0 = fmaf(wv.x, hv.x, a0);
      a1 = fmaf(wv.y, hv.y, a1);
      a2 = fmaf(wv.z, hv.z, a2);
      a3 = fmaf(wv.w, hv.w, a3);
    }
    hnew = tanhf((a0+a1)+(a2+a3) + xpC);
    hh[par ^ 1][j] = hnew;       // write other parity; no race with reads
    xpC = xpN;
    __syncthreads();             // the ONLY sync: intra-block barrier
  }
  hfin[(size_t)b*NHID + j] = hnew;   // h(2048)
}

// ---------------- output projection ----------------
__global__ __launch_bounds__(NOUT, 1)
void rnn_out_kernel(const float* __restrict__ hfin,
                    const float* __restrict__ Who,
                    const float* __restrict__ bho,
                    float* __restrict__ out)
{
  const int b = blockIdx.x;    // 64
  const int o = threadIdx.x;   // 128
  __shared__ __align__(16) float hB[NHID];
  for (int k = o; k < NHID; k += NOUT) hB[k] = hfin[(size_t)b*NHID + k];
  __syncthreads();
  const float* wr = Who + (size_t)o*NHID;
  float a0=0.f,a1=0.f,a2=0.f,a3=0.f;
  for (int k = 0; k < NHID; k += 4) {
    const float4 wv = *(const float4*)&wr[k];
    a0 = fmaf(wv.x, hB[k  ], a0);
    a1 = fmaf(wv.y, hB[k+1], a1);
    a2 = fmaf(wv.z, hB[k+2], a2);
    a3 = fmaf(wv.w, hB[k+3], a3);
  }
  out[(size_t)b*NOUT + o] = (a0+a1)+(a2+a3) + bho[o];
}

extern "C" void kernel_launch(void* const* d_in, const int* in_sizes, int n_in,
                              void* d_out, int out_size, void* d_ws, size_t ws_size,
                              hipStream_t stream)
{
  const float* x   = (const float*)d_in[0];
  const float* Wih = (const float*)d_in[1];
  const float* bih = (const float*)d_in[2];
  const float* Whh = (const float*)d_in[3];
  const float* bhh = (const float*)d_in[4];
  const float* Who = (const float*)d_in[5];
  const float* bho = (const float*)d_in[6];
  float* out = (float*)d_out;

  const size_t need_full = WQ_BYTES + HFIN_BYTES + XP_BYTES;

  if (ws_size >= need_full) {
    float* wq   = (float*)d_ws;
    float* hfin = (float*)((char*)d_ws + WQ_BYTES);
    float* xp   = (float*)((char*)d_ws + WQ_BYTES + HFIN_BYTES);
    wq_prep_kernel<<<dim3(128), dim3(512), 0, stream>>>(Whh, (float4*)wq);
    xproj_kernel<<<dim3(2048), dim3(256), 0, stream>>>(x, Wih, bih, bhh, xp);
    rnn_seq_kernel<0><<<dim3(BATCH), dim3(512), 0, stream>>>(xp, wq, hfin);
    rnn_out_kernel<<<dim3(BATCH), dim3(NOUT), 0, stream>>>(hfin, Who, bho, out);
  } else {
    // fallback: no Wq transpose buffer; stream Whh row-major directly
    float* hfin = (float*)d_ws;
    float* xp   = (float*)((char*)d_ws + HFIN_BYTES);
    xproj_kernel<<<dim3(2048), dim3(256), 0, stream>>>(x, Wih, bih, bhh, xp);
    rnn_seq_kernel<1><<<dim3(BATCH), dim3(512), 0, stream>>>(xp, Whh, hfin);
    rnn_out_kernel<<<dim3(BATCH), dim3(NOUT), 0, stream>>>(hfin, Who, bho, out);
  }
}

// Round 10
// 4388.139 us; speedup vs baseline: 7.1227x; 7.1227x over previous
//
#include <hip/hip_runtime.h>
#include <math.h>

#define SEQ   2048
#define BATCH 64
#define NIN   256
#define NHID  512
#define NOUT  128

#define NSL 4      // j-slices per batch row
#define JSL 128    // j's per slice

// wire: [par][b][slice][256 words]; value -> word pair (tag<<16|hi16,
// tag<<16|lo16). Self-validating words, system scope (sc0 sc1) only.
// (r4 lesson: sc0-only polls spin on stale L1 forever.)
#define WIRE_WORDS (2*BATCH*NSL*256)               // 131072 (512 KB)
#define WIRE_BYTES ((size_t)WIRE_WORDS*4)
#define HFIN_BYTES ((size_t)BATCH*NHID*4)          // 128 KB
#define XP_BYTES   ((size_t)SEQ*BATCH*NHID*4)      // 268.4 MB x-projection

typedef unsigned int u32;
typedef u32 u32x2 __attribute__((ext_vector_type(2)));

__device__ __forceinline__ u32x2 ld8_ic(const u32* p) {
  u32x2 r;
  asm volatile("global_load_dwordx2 %0, %1, off sc0 sc1"
               : "=v"(r) : "v"(p) : "memory");
  return r;
}
__device__ __forceinline__ void st8_ic(u32* p, u32x2 v) {
  asm volatile("global_store_dwordx2 %0, %1, off sc0 sc1"
               :: "v"(p), "v"(v) : "memory");
}
__device__ __forceinline__ void wait_vm0() {
  asm volatile("s_waitcnt vmcnt(0)" ::: "memory");
  __builtin_amdgcn_sched_barrier(0);   // uses stay after the wait (rule #18)
}

// ---------------- x-projection GEMM (verified r7/r8) ------------------------
// xp[row][j] = x[row,:]·Wih[j,:] + bih[j] + bhh[j];  row = t*64+b.
__global__ __launch_bounds__(256, 1)
void xproj_kernel(const float* __restrict__ x,
                  const float* __restrict__ Wih,
                  const float* __restrict__ bih,
                  const float* __restrict__ bhh,
                  float* __restrict__ xp)
{
  const int bj = blockIdx.x & 7;
  const int bm = blockIdx.x >> 3;
  const int tid = threadIdx.x;
  const int tx = tid & 15, ty = tid >> 4;

  __shared__ __align__(16) float  wT[NIN][68];
  __shared__ __align__(16) float4 xS[64][66];

  for (int it = 0; it < 64; ++it) {
    const int widx = tid + (it << 8);
    const int k = widx >> 6, j = widx & 63;
    wT[k][j] = Wih[(size_t)(bj*64 + j)*NIN + k];
  }
  const int jg = bj*64 + tx*4;
  float4 bv;
  bv.x = bih[jg+0]+bhh[jg+0]; bv.y = bih[jg+1]+bhh[jg+1];
  bv.z = bih[jg+2]+bhh[jg+2]; bv.w = bih[jg+3]+bhh[jg+3];
  __syncthreads();

  for (int mt = 0; mt < 8; ++mt) {
    const size_t r0 = (size_t)bm*512 + mt*64;
    for (int it = 0; it < 16; ++it) {
      const int f = tid + (it << 8);
      const int m = f >> 6, kq = f & 63;
      xS[m][kq] = *(const float4*)&x[(r0 + m)*NIN + (kq << 2)];
    }
    __syncthreads();

    float acc[4][4];
    #pragma unroll
    for (int q = 0; q < 4; ++q)
      #pragma unroll
      for (int jj = 0; jj < 4; ++jj) acc[q][jj] = 0.f;

    for (int kq = 0; kq < 64; ++kq) {
      const float4 xv0 = xS[ty*4+0][kq];
      const float4 xv1 = xS[ty*4+1][kq];
      const float4 xv2 = xS[ty*4+2][kq];
      const float4 xv3 = xS[ty*4+3][kq];
      #pragma unroll
      for (int i = 0; i < 4; ++i) {
        const float4 wv = *(const float4*)&wT[(kq<<2)+i][tx*4];
        const float xi0 = (i==0)?xv0.x:(i==1)?xv0.y:(i==2)?xv0.z:xv0.w;
        const float xi1 = (i==0)?xv1.x:(i==1)?xv1.y:(i==2)?xv1.z:xv1.w;
        const float xi2 = (i==0)?xv2.x:(i==1)?xv2.y:(i==2)?xv2.z:xv2.w;
        const float xi3 = (i==0)?xv3.x:(i==1)?xv3.y:(i==2)?xv3.z:xv3.w;
        acc[0][0]=fmaf(xi0,wv.x,acc[0][0]); acc[0][1]=fmaf(xi0,wv.y,acc[0][1]);
        acc[0][2]=fmaf(xi0,wv.z,acc[0][2]); acc[0][3]=fmaf(xi0,wv.w,acc[0][3]);
        acc[1][0]=fmaf(xi1,wv.x,acc[1][0]); acc[1][1]=fmaf(xi1,wv.y,acc[1][1]);
        acc[1][2]=fmaf(xi1,wv.z,acc[1][2]); acc[1][3]=fmaf(xi1,wv.w,acc[1][3]);
        acc[2][0]=fmaf(xi2,wv.x,acc[2][0]); acc[2][1]=fmaf(xi2,wv.y,acc[2][1]);
        acc[2][2]=fmaf(xi2,wv.z,acc[2][2]); acc[2][3]=fmaf(xi2,wv.w,acc[2][3]);
        acc[3][0]=fmaf(xi3,wv.x,acc[3][0]); acc[3][1]=fmaf(xi3,wv.y,acc[3][1]);
        acc[3][2]=fmaf(xi3,wv.z,acc[3][2]); acc[3][3]=fmaf(xi3,wv.w,acc[3][3]);
      }
    }
    #pragma unroll
    for (int q = 0; q < 4; ++q) {
      float4 o;
      o.x = acc[q][0]+bv.x; o.y = acc[q][1]+bv.y;
      o.z = acc[q][2]+bv.z; o.w = acc[q][3]+bv.w;
      *(float4*)&xp[(r0 + ty*4 + q)*NHID + jg] = o;
    }
    __syncthreads();
  }
}

// ---------------- 256-block recurrent kernel: W_hh fully in registers -------
// block (sj,b): 512 threads = 32 j-groups(4 j) x 16 k-chunks(32 k).
// Thread's W tile: 4j x 32k = 32 float4 = 128 VGPR (one-time load, zero
// per-step W traffic). h: full 512 values in LDS hS[16][36] (2-way max);
// own slice published to LDS+wire, 3 foreign slices staged from wire.
__global__ __launch_bounds__(512, 1)
void rnn_seq4_kernel(const float* __restrict__ xp,
                     const float* __restrict__ Whh,
                     u32* __restrict__ wire,
                     float* __restrict__ hfin)
{
  const int bid = blockIdx.x;        // sj*64 + b
  const int sj  = bid >> 6;          // 0..3 j-slice
  const int b   = bid & 63;          // batch row
  const int tid = threadIdx.x;
  const int jg  = tid >> 4;          // 0..31 j-group (4 j's)
  const int kl  = tid & 15;          // 0..15 k-chunk (32 k's)
  const int w   = tid >> 6, lane = tid & 63;

  // hS[par][k>>5][k&31]; row stride 36 -> bank 4*row+col: reads 2-way max
  __shared__ __align__(16) float hS[2][16][36];
  for (int i = tid; i < 16*36; i += 512) (&hS[0][0][0])[i] = 0.f;  // h(0)=0

  // ---- one-time W_hh register load: w{0..3}[i] = Whh[j0+jj][k0+4i..+3] ----
  const int j0 = sj*JSL + jg*4;
  const int k0 = kl*32;
  float4 w0[8], w1[8], w2[8], w3[8];
  #pragma unroll
  for (int i = 0; i < 8; ++i) {
    w0[i] = *(const float4*)&Whh[(size_t)(j0+0)*NHID + k0 + 4*i];
    w1[i] = *(const float4*)&Whh[(size_t)(j0+1)*NHID + k0 + 4*i];
    w2[i] = *(const float4*)&Whh[(size_t)(j0+2)*NHID + k0 + 4*i];
    w3[i] = *(const float4*)&Whh[(size_t)(j0+3)*NHID + k0 + 4*i];
  }

  const int jl = jg*4 + (kl & 3);          // the j this lane owns post-reduce
  const float* xpc = xp + (size_t)b*NHID + sj*JSL + jl;
  float xpC = xpc[0];

  // stager roles: waves 0..5 = 3 foreign slices x 2 waves (64 values each)
  const int sp = (sj + 1 + (w >> 1)) & 3;
  const int sm = ((w & 1) << 6) + lane;
  const int srow = sp*4 + (sm >> 5), scol = sm & 31;
  // own-slice LDS slot for publishers (kl<4)
  const int orow = sj*4 + (jl >> 5), ocol = jl & 31;

  __syncthreads();

  int par = 0;
  float hnew = 0.f;
  for (int t = 0; t < SEQ; ++t) {
    float xpN = 0.f;
    if (t + 1 < SEQ) xpN = xpc[(size_t)(t+1)*(BATCH*NHID)];  // lands in compute

    // ---- 4 j-partials over this thread's 32-k chunk (W in regs) ----
    float a0=0.f, a1=0.f, a2=0.f, a3=0.f;
    #pragma unroll
    for (int i = 0; i < 8; ++i) {
      const float4 hv = *(const float4*)&hS[par][kl][4*i];
      a0=fmaf(w0[i].x,hv.x,a0); a0=fmaf(w0[i].y,hv.y,a0);
      a0=fmaf(w0[i].z,hv.z,a0); a0=fmaf(w0[i].w,hv.w,a0);
      a1=fmaf(w1[i].x,hv.x,a1); a1=fmaf(w1[i].y,hv.y,a1);
      a1=fmaf(w1[i].z,hv.z,a1); a1=fmaf(w1[i].w,hv.w,a1);
      a2=fmaf(w2[i].x,hv.x,a2); a2=fmaf(w2[i].y,hv.y,a2);
      a2=fmaf(w2[i].z,hv.z,a2); a2=fmaf(w2[i].w,hv.w,a2);
      a3=fmaf(w3[i].x,hv.x,a3); a3=fmaf(w3[i].y,hv.y,a3);
      a3=fmaf(w3[i].z,hv.z,a3); a3=fmaf(w3[i].w,hv.w,a3);
    }

    // ---- width-16 butterfly over k-chunks; lane ends with j = jg*4+(kl&3) --
    {
      const float t0 = __shfl_xor(a0,1,16), t1 = __shfl_xor(a1,1,16);
      const float t2 = __shfl_xor(a2,1,16), t3 = __shfl_xor(a3,1,16);
      float b0, b1;
      if (kl & 1) { b0 = a1 + t1; b1 = a3 + t3; }
      else        { b0 = a0 + t0; b1 = a2 + t2; }
      const float u0 = __shfl_xor(b0,2,16), u1 = __shfl_xor(b1,2,16);
      float s = (kl & 2) ? (b1 + u1) : (b0 + u0);
      s += __shfl_xor(s, 4, 16);
      s += __shfl_xor(s, 8, 16);
      hnew = tanhf(s + xpC);
    }
    const int par2 = par ^ 1;

    if (t + 1 < SEQ) {
      // publish own slice: LDS + tagged wire (fire-and-forget)
      if (kl < 4) {
        hS[par2][orow][ocol] = hnew;
        const u32 bits = __float_as_uint(hnew);
        const u32 tag  = (u32)(t+1) << 16;
        u32x2 pv; pv.x = tag | (bits >> 16); pv.y = tag | (bits & 0xffffu);
        st8_ic(wire + ((((size_t)par2*BATCH + b)*NSL + sj) << 8) + (jl << 1), pv);
      }
      // stage foreign slices (waves 0..5); equality tags + watchdog
      if (w < 6) {
        const u32* src = wire + ((((size_t)par2*BATCH + b)*NSL + sp) << 8) + (sm << 1);
        const u32 tg = (u32)(t+1);
        u32x2 v = ld8_ic(src);
        wait_vm0();
        int guard = 1 << 17;
        while (!__all((v.x >> 16) == tg && (v.y >> 16) == tg)) {
          if (--guard == 0) break;     // bug => absmax fail, not hang
          v = ld8_ic(src);
          wait_vm0();
        }
        hS[par2][srow][scol] = __uint_as_float((v.x << 16) | (v.y & 0xffffu));
      }
      __syncthreads();                 // hS[par2] complete; only barrier/step
      xpC = xpN;
      par = par2;
    }
  }
  if (kl < 4) hfin[(size_t)b*NHID + sj*JSL + jl] = hnew;   // h(2048)
}

// ---------------- fallback (r8, known-pass): batch-split, W row-major -------
__global__ __launch_bounds__(512, 2)
void rnn_seq_fb_kernel(const float* __restrict__ xp,
                       const float* __restrict__ Whh,
                       float* __restrict__ hfin)
{
  const int b = blockIdx.x;
  const int j = threadIdx.x;
  __shared__ __align__(16) float hh[2][NHID];
  hh[0][j] = 0.f;
  const float* wrow = Whh + (size_t)j*NHID;
  const float* xcol = xp + (size_t)b*NHID + j;
  float xpC = xcol[0];
  float hnew = 0.f;
  __syncthreads();
  for (int t = 0; t < SEQ; ++t) {
    const int par = t & 1;
    float xpN = 0.f;
    if (t + 1 < SEQ) xpN = xcol[(size_t)(t+1)*(BATCH*NHID)];
    const float* hA = hh[par];
    float a0=0.f,a1=0.f,a2=0.f,a3=0.f;
    #pragma unroll 8
    for (int kq = 0; kq < 128; ++kq) {
      const float4 wv = *(const float4*)&wrow[kq << 2];
      const float4 hv = *(const float4*)&hA[kq << 2];
      a0 = fmaf(wv.x, hv.x, a0);
      a1 = fmaf(wv.y, hv.y, a1);
      a2 = fmaf(wv.z, hv.z, a2);
      a3 = fmaf(wv.w, hv.w, a3);
    }
    hnew = tanhf((a0+a1)+(a2+a3) + xpC);
    hh[par ^ 1][j] = hnew;
    xpC = xpN;
    __syncthreads();
  }
  hfin[(size_t)b*NHID + j] = hnew;
}

// ---------------- output projection ----------------
__global__ __launch_bounds__(NOUT, 1)
void rnn_out_kernel(const float* __restrict__ hfin,
                    const float* __restrict__ Who,
                    const float* __restrict__ bho,
                    float* __restrict__ out)
{
  const int b = blockIdx.x;
  const int o = threadIdx.x;
  __shared__ __align__(16) float hB[NHID];
  for (int k = o; k < NHID; k += NOUT) hB[k] = hfin[(size_t)b*NHID + k];
  __syncthreads();
  const float* wr = Who + (size_t)o*NHID;
  float a0=0.f,a1=0.f,a2=0.f,a3=0.f;
  for (int k = 0; k < NHID; k += 4) {
    const float4 wv = *(const float4*)&wr[k];
    a0 = fmaf(wv.x, hB[k  ], a0);
    a1 = fmaf(wv.y, hB[k+1], a1);
    a2 = fmaf(wv.z, hB[k+2], a2);
    a3 = fmaf(wv.w, hB[k+3], a3);
  }
  out[(size_t)b*NOUT + o] = (a0+a1)+(a2+a3) + bho[o];
}

extern "C" void kernel_launch(void* const* d_in, const int* in_sizes, int n_in,
                              void* d_out, int out_size, void* d_ws, size_t ws_size,
                              hipStream_t stream)
{
  const float* x   = (const float*)d_in[0];
  const float* Wih = (const float*)d_in[1];
  const float* bih = (const float*)d_in[2];
  const float* Whh = (const float*)d_in[3];
  const float* bhh = (const float*)d_in[4];
  const float* Who = (const float*)d_in[5];
  const float* bho = (const float*)d_in[6];
  float* out = (float*)d_out;

  const size_t need = WIRE_BYTES + HFIN_BYTES + XP_BYTES;

  if (ws_size >= need) {
    u32*   wire = (u32*)d_ws;
    float* hfin = (float*)((char*)d_ws + WIRE_BYTES);
    float* xp   = (float*)((char*)d_ws + WIRE_BYTES + HFIN_BYTES);

    hipMemsetAsync(wire, 0, WIRE_BYTES, stream);   // tags 0; step0 wants tag 1
    xproj_kernel  <<<dim3(2048), dim3(256), 0, stream>>>(x, Wih, bih, bhh, xp);
    rnn_seq4_kernel<<<dim3(NSL*BATCH), dim3(512), 0, stream>>>(xp, Whh, wire, hfin);
    rnn_out_kernel<<<dim3(BATCH), dim3(NOUT), 0, stream>>>(hfin, Who, bho, out);
  } else {
    float* hfin = (float*)d_ws;
    float* xp   = (float*)((char*)d_ws + HFIN_BYTES);
    xproj_kernel<<<dim3(2048), dim3(256), 0, stream>>>(x, Wih, bih, bhh, xp);
    rnn_seq_fb_kernel<<<dim3(BATCH), dim3(512), 0, stream>>>(xp, Whh, hfin);
    rnn_out_kernel<<<dim3(BATCH), dim3(NOUT), 0, stream>>>(hfin, Who, bho, out);
  }
}

// Round 11
// 3993.925 us; speedup vs baseline: 7.8258x; 1.0987x over previous
//
#include <hip/hip_runtime.h>
#include <math.h>

#define SEQ   2048
#define BATCH 64
#define NIN   256
#define NHID  512
#define NOUT  128

#define NSL 4      // j-slices per batch row
#define JSL 128    // j's per slice

// wire: [par][b][slice][256 words]; value -> word pair (tag<<16|hi16,
// tag<<16|lo16). Self-validating words, system scope (sc0 sc1) only.
// (r4 lesson: sc0-only polls spin on stale L1 forever.)
#define WIRE_WORDS (2*BATCH*NSL*256)               // 131072 (512 KB)
#define WIRE_BYTES ((size_t)WIRE_WORDS*4)
#define HFIN_BYTES ((size_t)BATCH*NHID*4)          // 128 KB
#define XP_BYTES   ((size_t)SEQ*BATCH*NHID*4)      // 268.4 MB x-projection

typedef unsigned int u32;
typedef u32 u32x2 __attribute__((ext_vector_type(2)));

__device__ __forceinline__ u32x2 ld8_ic(const u32* p) {
  u32x2 r;
  asm volatile("global_load_dwordx2 %0, %1, off sc0 sc1"
               : "=v"(r) : "v"(p) : "memory");
  return r;
}
__device__ __forceinline__ void st8_ic(u32* p, u32x2 v) {
  asm volatile("global_store_dwordx2 %0, %1, off sc0 sc1"
               :: "v"(p), "v"(v) : "memory");
}
__device__ __forceinline__ void wait_vm0() {
  asm volatile("s_waitcnt vmcnt(0)" ::: "memory");
  __builtin_amdgcn_sched_barrier(0);   // uses stay after the wait (rule #18)
}

// tanh(x) = 1 - 2/(exp2(2*log2e*x)+1): 5 VALU ops, exact +-1 saturation,
// ~1e-6 abs error (vs ~1e-3 existing reorder noise). Replaces libm tanhf.
__device__ __forceinline__ float fast_tanh(float x) {
  const float e = __builtin_amdgcn_exp2f(x * 2.8853900817779268f);
  const float r = __builtin_amdgcn_rcpf(e + 1.0f);
  return fmaf(-2.0f, r, 1.0f);
}

// ---------------- x-projection GEMM: 512 thr (2 waves/SIMD latency overlap) --
// xp[row][j] = x[row,:]·Wih[j,:] + bih[j] + bhh[j];  row = t*64+b.
// Same tiling/accumulation order as the verified r7 kernel; thread = 2m x 4j.
__global__ __launch_bounds__(512, 1)
void xproj_kernel(const float* __restrict__ x,
                  const float* __restrict__ Wih,
                  const float* __restrict__ bih,
                  const float* __restrict__ bhh,
                  float* __restrict__ xp)
{
  const int bj = blockIdx.x & 7;        // j-tile (64 j)
  const int bm = blockIdx.x >> 3;       // m-group (512 rows)
  const int tid = threadIdx.x;
  const int tx = tid & 15, ty = tid >> 4;   // tx: 4-j group, ty: 2-row group

  __shared__ __align__(16) float  wT[NIN][68];   // [k][j] transposed
  __shared__ __align__(16) float4 xS[64][66];    // [m][kq] k-vectorized

  for (int it = 0; it < 32; ++it) {
    const int widx = tid + (it << 9);
    const int k = widx >> 6, j = widx & 63;
    wT[k][j] = Wih[(size_t)(bj*64 + j)*NIN + k];
  }
  const int jg = bj*64 + tx*4;
  float4 bv;
  bv.x = bih[jg+0]+bhh[jg+0]; bv.y = bih[jg+1]+bhh[jg+1];
  bv.z = bih[jg+2]+bhh[jg+2]; bv.w = bih[jg+3]+bhh[jg+3];
  __syncthreads();

  for (int mt = 0; mt < 8; ++mt) {
    const size_t r0 = (size_t)bm*512 + mt*64;
    for (int it = 0; it < 8; ++it) {
      const int f = tid + (it << 9);
      const int m = f >> 6, kq = f & 63;
      xS[m][kq] = *(const float4*)&x[(r0 + m)*NIN + (kq << 2)];
    }
    __syncthreads();

    float acc[2][4];
    #pragma unroll
    for (int q = 0; q < 2; ++q)
      #pragma unroll
      for (int jj = 0; jj < 4; ++jj) acc[q][jj] = 0.f;

    for (int kq = 0; kq < 64; ++kq) {
      const float4 xv0 = xS[ty*2+0][kq];
      const float4 xv1 = xS[ty*2+1][kq];
      #pragma unroll
      for (int i = 0; i < 4; ++i) {
        const float4 wv = *(const float4*)&wT[(kq<<2)+i][tx*4];
        const float xi0 = (i==0)?xv0.x:(i==1)?xv0.y:(i==2)?xv0.z:xv0.w;
        const float xi1 = (i==0)?xv1.x:(i==1)?xv1.y:(i==2)?xv1.z:xv1.w;
        acc[0][0]=fmaf(xi0,wv.x,acc[0][0]); acc[0][1]=fmaf(xi0,wv.y,acc[0][1]);
        acc[0][2]=fmaf(xi0,wv.z,acc[0][2]); acc[0][3]=fmaf(xi0,wv.w,acc[0][3]);
        acc[1][0]=fmaf(xi1,wv.x,acc[1][0]); acc[1][1]=fmaf(xi1,wv.y,acc[1][1]);
        acc[1][2]=fmaf(xi1,wv.z,acc[1][2]); acc[1][3]=fmaf(xi1,wv.w,acc[1][3]);
      }
    }
    float4 o0, o1;
    o0.x = acc[0][0]+bv.x; o0.y = acc[0][1]+bv.y;
    o0.z = acc[0][2]+bv.z; o0.w = acc[0][3]+bv.w;
    o1.x = acc[1][0]+bv.x; o1.y = acc[1][1]+bv.y;
    o1.z = acc[1][2]+bv.z; o1.w = acc[1][3]+bv.w;
    *(float4*)&xp[(r0 + ty*2 + 0)*NHID + jg] = o0;
    *(float4*)&xp[(r0 + ty*2 + 1)*NHID + jg] = o1;
    __syncthreads();
  }
}

// ---------------- 256-block recurrent kernel: W_hh in registers -------------
// block (sj,b): 512 threads = 32 j-groups(4 j) x 16 k-chunks(32 k).
// 2-step unrolled loop: all wire/LDS/xp addresses hoisted per parity.
__global__ __launch_bounds__(512, 1)
void rnn_seq4_kernel(const float* __restrict__ xp,
                     const float* __restrict__ Whh,
                     u32* __restrict__ wire,
                     float* __restrict__ hfin)
{
  const int bid = blockIdx.x;        // sj*64 + b
  const int sj  = bid >> 6;          // 0..3 j-slice
  const int b   = bid & 63;          // batch row
  const int tid = threadIdx.x;
  const int jg  = tid >> 4;          // 0..31 j-group (4 j's)
  const int kl  = tid & 15;          // 0..15 k-chunk (32 k's)
  const int w   = tid >> 6, lane = tid & 63;

  // hS[par][k>>5][k&31]; stride 36 -> measured 0 bank conflicts (r10)
  __shared__ __align__(16) float hS[2][16][36];
  for (int i = tid; i < 16*36; i += 512) (&hS[0][0][0])[i] = 0.f;  // h(0)=0

  // ---- one-time W_hh register tile: 4j x 32k = 128 VGPR ----
  const int j0 = sj*JSL + jg*4;
  const int k0 = kl*32;
  float4 w0[8], w1[8], w2[8], w3[8];
  #pragma unroll
  for (int i = 0; i < 8; ++i) {
    w0[i] = *(const float4*)&Whh[(size_t)(j0+0)*NHID + k0 + 4*i];
    w1[i] = *(const float4*)&Whh[(size_t)(j0+1)*NHID + k0 + 4*i];
    w2[i] = *(const float4*)&Whh[(size_t)(j0+2)*NHID + k0 + 4*i];
    w3[i] = *(const float4*)&Whh[(size_t)(j0+3)*NHID + k0 + 4*i];
  }

  const int jl = jg*4 + (kl & 3);          // lane's output j (in block)
  const float* xptr = xp + (size_t)b*NHID + sj*JSL + jl;
  float xpC = *xptr;
  xptr += BATCH*NHID;                      // -> t=1

  // stager roles: waves 0..5 = 3 foreign slices x 2 waves (64 values each)
  const int sp = (sj + 1 + (w >> 1)) & 3;
  const int sm = ((w & 1) << 6) + lane;
  const int srow = sp*4 + (sm >> 5), scol = sm & 31;
  const int orow = sj*4 + (jl >> 5), ocol = jl & 31;

  // ---- hoisted per-parity pointers (all loop-invariant) ----
  const float* dA0 = &hS[0][kl][0];
  const float* dA1 = &hS[1][kl][0];
  float* pL0 = &hS[0][orow][ocol];
  float* pL1 = &hS[1][orow][ocol];
  float* sd0 = &hS[0][srow][scol];
  float* sd1 = &hS[1][srow][scol];
  u32* wo0 = wire + ((((size_t)0*BATCH + b)*NSL + sj) << 8) + (jl << 1);
  u32* wo1 = wire + ((((size_t)1*BATCH + b)*NSL + sj) << 8) + (jl << 1);
  const u32* wf0 = wire + ((((size_t)0*BATCH + b)*NSL + sp) << 8) + (sm << 1);
  const u32* wf1 = wire + ((((size_t)1*BATCH + b)*NSL + sp) << 8) + (sm << 1);

  __syncthreads();

  float hlast = 0.f;

#define RSTEP(T, DA, PL, WO, WF, SD)                                          \
  {                                                                           \
    const bool last_ = (T) == SEQ - 1;                                        \
    float xpN = 0.f;                                                          \
    if (!last_) { xpN = *xptr; xptr += BATCH*NHID; }                          \
    float a0=0.f, a1=0.f, a2=0.f, a3=0.f;                                     \
    _Pragma("unroll")                                                         \
    for (int i = 0; i < 8; ++i) {                                             \
      const float4 hv = *(const float4*)((DA) + 4*i);                         \
      a0=fmaf(w0[i].x,hv.x,a0); a0=fmaf(w0[i].y,hv.y,a0);                     \
      a0=fmaf(w0[i].z,hv.z,a0); a0=fmaf(w0[i].w,hv.w,a0);                     \
      a1=fmaf(w1[i].x,hv.x,a1); a1=fmaf(w1[i].y,hv.y,a1);                     \
      a1=fmaf(w1[i].z,hv.z,a1); a1=fmaf(w1[i].w,hv.w,a1);                     \
      a2=fmaf(w2[i].x,hv.x,a2); a2=fmaf(w2[i].y,hv.y,a2);                     \
      a2=fmaf(w2[i].z,hv.z,a2); a2=fmaf(w2[i].w,hv.w,a2);                     \
      a3=fmaf(w3[i].x,hv.x,a3); a3=fmaf(w3[i].y,hv.y,a3);                     \
      a3=fmaf(w3[i].z,hv.z,a3); a3=fmaf(w3[i].w,hv.w,a3);                     \
    }                                                                         \
    float s_;                                                                 \
    {                                                                         \
      const float t0_ = __shfl_xor(a0,1,4), t1_ = __shfl_xor(a1,1,4);         \
      const float t2_ = __shfl_xor(a2,1,4), t3_ = __shfl_xor(a3,1,4);         \
      float b0_, b1_;                                                         \
      if (kl & 1) { b0_ = a1 + t1_; b1_ = a3 + t3_; }                         \
      else        { b0_ = a0 + t0_; b1_ = a2 + t2_; }                         \
      const float u0_ = __shfl_xor(b0_,2,4), u1_ = __shfl_xor(b1_,2,4);       \
      s_ = (kl & 2) ? (b1_ + u1_) : (b0_ + u0_);                              \
      s_ += __shfl_xor(s_, 4, 16);                                            \
      s_ += __shfl_xor(s_, 8, 16);                                            \
    }                                                                         \
    const float hn_ = fast_tanh(s_ + xpC);                                    \
    if (!last_) {                                                             \
      const u32 tg_ = (u32)(T) + 1u;                                          \
      if (kl < 4) {                                                           \
        *(PL) = hn_;                                                          \
        const u32 bits_ = __float_as_uint(hn_);                               \
        u32x2 pv_;                                                            \
        pv_.x = (tg_<<16) | (bits_>>16);                                      \
        pv_.y = (tg_<<16) | (bits_ & 0xffffu);                                \
        st8_ic((WO), pv_);                                                    \
      }                                                                       \
      if (w < 6) {                                                            \
        u32x2 v_ = ld8_ic(WF); wait_vm0();                                    \
        int guard_ = 1 << 17;                                                 \
        while (!__all((v_.x>>16)==tg_ && (v_.y>>16)==tg_)) {                  \
          if (--guard_ == 0) break;   /* bug => absmax fail, not hang */      \
          v_ = ld8_ic(WF); wait_vm0();                                        \
        }                                                                     \
        *(SD) = __uint_as_float((v_.x<<16) | (v_.y & 0xffffu));               \
      }                                                                       \
      __syncthreads();               /* hS[next par] complete */              \
      xpC = xpN;                                                              \
    }                                                                         \
    hlast = hn_;                                                              \
  }

  for (int t = 0; t < SEQ; t += 2) {
    RSTEP(t,     dA0, pL1, wo1, wf1, sd1);   // even: read par0, write par1
    RSTEP(t + 1, dA1, pL0, wo0, wf0, sd0);   // odd:  read par1, write par0
  }
#undef RSTEP

  if (kl < 4) hfin[(size_t)b*NHID + sj*JSL + jl] = hlast;   // h(2048)
}

// ---------------- fallback (r8, known-pass): batch-split, W row-major -------
__global__ __launch_bounds__(512, 2)
void rnn_seq_fb_kernel(const float* __restrict__ xp,
                       const float* __restrict__ Whh,
                       float* __restrict__ hfin)
{
  const int b = blockIdx.x;
  const int j = threadIdx.x;
  __shared__ __align__(16) float hh[2][NHID];
  hh[0][j] = 0.f;
  const float* wrow = Whh + (size_t)j*NHID;
  const float* xcol = xp + (size_t)b*NHID + j;
  float xpC = xcol[0];
  float hnew = 0.f;
  __syncthreads();
  for (int t = 0; t < SEQ; ++t) {
    const int par = t & 1;
    float xpN = 0.f;
    if (t + 1 < SEQ) xpN = xcol[(size_t)(t+1)*(BATCH*NHID)];
    const float* hA = hh[par];
    float a0=0.f,a1=0.f,a2=0.f,a3=0.f;
    #pragma unroll 8
    for (int kq = 0; kq < 128; ++kq) {
      const float4 wv = *(const float4*)&wrow[kq << 2];
      const float4 hv = *(const float4*)&hA[kq << 2];
      a0 = fmaf(wv.x, hv.x, a0);
      a1 = fmaf(wv.y, hv.y, a1);
      a2 = fmaf(wv.z, hv.z, a2);
      a3 = fmaf(wv.w, hv.w, a3);
    }
    hnew = tanhf((a0+a1)+(a2+a3) + xpC);
    hh[par ^ 1][j] = hnew;
    xpC = xpN;
    __syncthreads();
  }
  hfin[(size_t)b*NHID + j] = hnew;
}

// ---------------- output projection ----------------
__global__ __launch_bounds__(NOUT, 1)
void rnn_out_kernel(const float* __restrict__ hfin,
                    const float* __restrict__ Who,
                    const float* __restrict__ bho,
                    float* __restrict__ out)
{
  const int b = blockIdx.x;
  const int o = threadIdx.x;
  __shared__ __align__(16) float hB[NHID];
  for (int k = o; k < NHID; k += NOUT) hB[k] = hfin[(size_t)b*NHID + k];
  __syncthreads();
  const float* wr = Who + (size_t)o*NHID;
  float a0=0.f,a1=0.f,a2=0.f,a3=0.f;
  for (int k = 0; k < NHID; k += 4) {
    const float4 wv = *(const float4*)&wr[k];
    a0 = fmaf(wv.x, hB[k  ], a0);
    a1 = fmaf(wv.y, hB[k+1], a1);
    a2 = fmaf(wv.z, hB[k+2], a2);
    a3 = fmaf(wv.w, hB[k+3], a3);
  }
  out[(size_t)b*NOUT + o] = (a0+a1)+(a2+a3) + bho[o];
}

extern "C" void kernel_launch(void* const* d_in, const int* in_sizes, int n_in,
                              void* d_out, int out_size, void* d_ws, size_t ws_size,
                              hipStream_t stream)
{
  const float* x   = (const float*)d_in[0];
  const float* Wih = (const float*)d_in[1];
  const float* bih = (const float*)d_in[2];
  const float* Whh = (const float*)d_in[3];
  const float* bhh = (const float*)d_in[4];
  const float* Who = (const float*)d_in[5];
  const float* bho = (const float*)d_in[6];
  float* out = (float*)d_out;

  const size_t need = WIRE_BYTES + HFIN_BYTES + XP_BYTES;

  if (ws_size >= need) {
    u32*   wire = (u32*)d_ws;
    float* hfin = (float*)((char*)d_ws + WIRE_BYTES);
    float* xp   = (float*)((char*)d_ws + WIRE_BYTES + HFIN_BYTES);

    hipMemsetAsync(wire, 0, WIRE_BYTES, stream);   // tags 0; step0 wants tag 1
    xproj_kernel  <<<dim3(2048), dim3(512), 0, stream>>>(x, Wih, bih, bhh, xp);
    rnn_seq4_kernel<<<dim3(NSL*BATCH), dim3(512), 0, stream>>>(xp, Whh, wire, hfin);
    rnn_out_kernel<<<dim3(BATCH), dim3(NOUT), 0, stream>>>(hfin, Who, bho, out);
  } else {
    float* hfin = (float*)d_ws;
    float* xp   = (float*)((char*)d_ws + HFIN_BYTES);
    xproj_kernel<<<dim3(2048), dim3(512), 0, stream>>>(x, Wih, bih, bhh, xp);
    rnn_seq_fb_kernel<<<dim3(BATCH), dim3(512), 0, stream>>>(xp, Whh, hfin);
    rnn_out_kernel<<<dim3(BATCH), dim3(NOUT), 0, stream>>>(hfin, Who, bho, out);
  }
}

// Round 12
// 3989.262 us; speedup vs baseline: 7.8349x; 1.0012x over previous
//
#include <hip/hip_runtime.h>
#include <math.h>

#define SEQ   2048
#define BATCH 64
#define NIN   256
#define NHID  512
#define NOUT  128

#define NSL 4      // j-slices per batch row
#define JSL 128    // j's per slice

// wire: [par][b][slice][256 words]; value -> word pair (tag<<16|hi16,
// tag<<16|lo16). Self-validating words, system scope (sc0 sc1) only.
// (r4 lesson: sc0-only polls spin on stale L1 forever.)
#define WIRE_WORDS (2*BATCH*NSL*256)               // 131072 (512 KB)
#define WIRE_BYTES ((size_t)WIRE_WORDS*4)
#define HFIN_BYTES ((size_t)BATCH*NHID*4)          // 128 KB
#define XP_BYTES   ((size_t)SEQ*BATCH*NHID*4)      // 268.4 MB x-projection

typedef unsigned int u32;
typedef u32 u32x2 __attribute__((ext_vector_type(2)));

__device__ __forceinline__ u32x2 ld8_ic(const u32* p) {
  u32x2 r;
  asm volatile("global_load_dwordx2 %0, %1, off sc0 sc1"
               : "=v"(r) : "v"(p) : "memory");
  return r;
}
__device__ __forceinline__ void st8_ic(u32* p, u32x2 v) {
  asm volatile("global_store_dwordx2 %0, %1, off sc0 sc1"
               :: "v"(p), "v"(v) : "memory");
}
__device__ __forceinline__ void wait_vm0() {
  asm volatile("s_waitcnt vmcnt(0)" ::: "memory");
  __builtin_amdgcn_sched_barrier(0);   // uses stay after the wait (rule #18)
}
// pin a float4 in VGPRs: value becomes asm-defined -> compiler cannot
// rematerialize it from its originating global load inside the loop.
__device__ __forceinline__ void pin4(float4& v) {
  asm volatile("" : "+v"(v.x), "+v"(v.y), "+v"(v.z), "+v"(v.w));
}

// tanh(x) = 1 - 2/(exp2(2*log2e*x)+1): 5 VALU ops, exact +-1 saturation,
// ~1e-6 abs error (vs ~1e-3 existing reorder noise).
__device__ __forceinline__ float fast_tanh(float x) {
  const float e = __builtin_amdgcn_exp2f(x * 2.8853900817779268f);
  const float r = __builtin_amdgcn_rcpf(e + 1.0f);
  return fmaf(-2.0f, r, 1.0f);
}

// ---------------- x-projection GEMM (verified r11) --------------------------
// xp[row][j] = x[row,:]·Wih[j,:] + bih[j] + bhh[j];  row = t*64+b.
__global__ __launch_bounds__(512, 1)
void xproj_kernel(const float* __restrict__ x,
                  const float* __restrict__ Wih,
                  const float* __restrict__ bih,
                  const float* __restrict__ bhh,
                  float* __restrict__ xp)
{
  const int bj = blockIdx.x & 7;        // j-tile (64 j)
  const int bm = blockIdx.x >> 3;       // m-group (512 rows)
  const int tid = threadIdx.x;
  const int tx = tid & 15, ty = tid >> 4;   // tx: 4-j group, ty: 2-row group

  __shared__ __align__(16) float  wT[NIN][68];   // [k][j] transposed
  __shared__ __align__(16) float4 xS[64][66];    // [m][kq] k-vectorized

  for (int it = 0; it < 32; ++it) {
    const int widx = tid + (it << 9);
    const int k = widx >> 6, j = widx & 63;
    wT[k][j] = Wih[(size_t)(bj*64 + j)*NIN + k];
  }
  const int jg = bj*64 + tx*4;
  float4 bv;
  bv.x = bih[jg+0]+bhh[jg+0]; bv.y = bih[jg+1]+bhh[jg+1];
  bv.z = bih[jg+2]+bhh[jg+2]; bv.w = bih[jg+3]+bhh[jg+3];
  __syncthreads();

  for (int mt = 0; mt < 8; ++mt) {
    const size_t r0 = (size_t)bm*512 + mt*64;
    for (int it = 0; it < 8; ++it) {
      const int f = tid + (it << 9);
      const int m = f >> 6, kq = f & 63;
      xS[m][kq] = *(const float4*)&x[(r0 + m)*NIN + (kq << 2)];
    }
    __syncthreads();

    float acc[2][4];
    #pragma unroll
    for (int q = 0; q < 2; ++q)
      #pragma unroll
      for (int jj = 0; jj < 4; ++jj) acc[q][jj] = 0.f;

    for (int kq = 0; kq < 64; ++kq) {
      const float4 xv0 = xS[ty*2+0][kq];
      const float4 xv1 = xS[ty*2+1][kq];
      #pragma unroll
      for (int i = 0; i < 4; ++i) {
        const float4 wv = *(const float4*)&wT[(kq<<2)+i][tx*4];
        const float xi0 = (i==0)?xv0.x:(i==1)?xv0.y:(i==2)?xv0.z:xv0.w;
        const float xi1 = (i==0)?xv1.x:(i==1)?xv1.y:(i==2)?xv1.z:xv1.w;
        acc[0][0]=fmaf(xi0,wv.x,acc[0][0]); acc[0][1]=fmaf(xi0,wv.y,acc[0][1]);
        acc[0][2]=fmaf(xi0,wv.z,acc[0][2]); acc[0][3]=fmaf(xi0,wv.w,acc[0][3]);
        acc[1][0]=fmaf(xi1,wv.x,acc[1][0]); acc[1][1]=fmaf(xi1,wv.y,acc[1][1]);
        acc[1][2]=fmaf(xi1,wv.z,acc[1][2]); acc[1][3]=fmaf(xi1,wv.w,acc[1][3]);
      }
    }
    float4 o0, o1;
    o0.x = acc[0][0]+bv.x; o0.y = acc[0][1]+bv.y;
    o0.z = acc[0][2]+bv.z; o0.w = acc[0][3]+bv.w;
    o1.x = acc[1][0]+bv.x; o1.y = acc[1][1]+bv.y;
    o1.z = acc[1][2]+bv.z; o1.w = acc[1][3]+bv.w;
    *(float4*)&xp[(r0 + ty*2 + 0)*NHID + jg] = o0;
    *(float4*)&xp[(r0 + ty*2 + 1)*NHID + jg] = o1;
    __syncthreads();
  }
}

// ---------------- 256-block recurrent kernel: W_hh pinned in registers ------
// block (sj,b): 512 threads = 32 j-groups(4 j) x 16 k-chunks(32 k).
// 8 waves/CU = exactly 2 waves/SIMD -> pin waves_per_eu(2,2): VGPR budget
// 256, so the 128-VGPR W tile stays resident (r11: compiler remat'd it).
__global__ __launch_bounds__(512)
__attribute__((amdgpu_waves_per_eu(2, 2)))
void rnn_seq4_kernel(const float* __restrict__ xp,
                     const float* __restrict__ Whh,
                     u32* __restrict__ wire,
                     float* __restrict__ hfin)
{
  const int bid = blockIdx.x;        // sj*64 + b
  const int sj  = bid >> 6;          // 0..3 j-slice
  const int b   = bid & 63;          // batch row
  const int tid = threadIdx.x;
  const int jg  = tid >> 4;          // 0..31 j-group (4 j's)
  const int kl  = tid & 15;          // 0..15 k-chunk (32 k's)
  const int w   = tid >> 6, lane = tid & 63;

  // hS[par][k>>5][k&31]; stride 36 -> measured 0 bank conflicts (r10/r11)
  __shared__ __align__(16) float hS[2][16][36];
  for (int i = tid; i < 16*36; i += 512) (&hS[0][0][0])[i] = 0.f;  // h(0)=0

  // ---- one-time W_hh register tile: 4j x 32k = 128 VGPR, pinned ----
  const int j0 = sj*JSL + jg*4;
  const int k0 = kl*32;
  float4 w0[8], w1[8], w2[8], w3[8];
  #pragma unroll
  for (int i = 0; i < 8; ++i) {
    w0[i] = *(const float4*)&Whh[(size_t)(j0+0)*NHID + k0 + 4*i];
    w1[i] = *(const float4*)&Whh[(size_t)(j0+1)*NHID + k0 + 4*i];
    w2[i] = *(const float4*)&Whh[(size_t)(j0+2)*NHID + k0 + 4*i];
    w3[i] = *(const float4*)&Whh[(size_t)(j0+3)*NHID + k0 + 4*i];
  }
  #pragma unroll
  for (int i = 0; i < 8; ++i) { pin4(w0[i]); pin4(w1[i]); pin4(w2[i]); pin4(w3[i]); }

  const int jl = jg*4 + (kl & 3);          // lane's output j (in block)
  const float* xptr = xp + (size_t)b*NHID + sj*JSL + jl;
  float xpC = *xptr;
  xptr += BATCH*NHID;                      // -> t=1

  // stager roles: waves 0..5 = 3 foreign slices x 2 waves (64 values each)
  const int sp = (sj + 1 + (w >> 1)) & 3;
  const int sm = ((w & 1) << 6) + lane;
  const int srow = sp*4 + (sm >> 5), scol = sm & 31;
  const int orow = sj*4 + (jl >> 5), ocol = jl & 31;

  // ---- hoisted per-parity pointers (all loop-invariant) ----
  const float* dA0 = &hS[0][kl][0];
  const float* dA1 = &hS[1][kl][0];
  float* pL0 = &hS[0][orow][ocol];
  float* pL1 = &hS[1][orow][ocol];
  float* sd0 = &hS[0][srow][scol];
  float* sd1 = &hS[1][srow][scol];
  u32* wo0 = wire + ((((size_t)0*BATCH + b)*NSL + sj) << 8) + (jl << 1);
  u32* wo1 = wire + ((((size_t)1*BATCH + b)*NSL + sj) << 8) + (jl << 1);
  const u32* wf0 = wire + ((((size_t)0*BATCH + b)*NSL + sp) << 8) + (sm << 1);
  const u32* wf1 = wire + ((((size_t)1*BATCH + b)*NSL + sp) << 8) + (sm << 1);

  __syncthreads();

  float hlast = 0.f;

#define RSTEP(T, DA, PL, WO, WF, SD)                                          \
  {                                                                           \
    const bool last_ = (T) == SEQ - 1;                                        \
    float xpN = 0.f;                                                          \
    if (!last_) { xpN = *xptr; xptr += BATCH*NHID; }                          \
    float a0=0.f, a1=0.f, a2=0.f, a3=0.f;                                     \
    _Pragma("unroll")                                                         \
    for (int i = 0; i < 8; ++i) {                                             \
      const float4 hv = *(const float4*)((DA) + 4*i);                         \
      a0=fmaf(w0[i].x,hv.x,a0); a0=fmaf(w0[i].y,hv.y,a0);                     \
      a0=fmaf(w0[i].z,hv.z,a0); a0=fmaf(w0[i].w,hv.w,a0);                     \
      a1=fmaf(w1[i].x,hv.x,a1); a1=fmaf(w1[i].y,hv.y,a1);                     \
      a1=fmaf(w1[i].z,hv.z,a1); a1=fmaf(w1[i].w,hv.w,a1);                     \
      a2=fmaf(w2[i].x,hv.x,a2); a2=fmaf(w2[i].y,hv.y,a2);                     \
      a2=fmaf(w2[i].z,hv.z,a2); a2=fmaf(w2[i].w,hv.w,a2);                     \
      a3=fmaf(w3[i].x,hv.x,a3); a3=fmaf(w3[i].y,hv.y,a3);                     \
      a3=fmaf(w3[i].z,hv.z,a3); a3=fmaf(w3[i].w,hv.w,a3);                     \
    }                                                                         \
    float s_;                                                                 \
    {                                                                         \
      const float t0_ = __shfl_xor(a0,1,4), t1_ = __shfl_xor(a1,1,4);         \
      const float t2_ = __shfl_xor(a2,1,4), t3_ = __shfl_xor(a3,1,4);         \
      float b0_, b1_;                                                         \
      if (kl & 1) { b0_ = a1 + t1_; b1_ = a3 + t3_; }                         \
      else        { b0_ = a0 + t0_; b1_ = a2 + t2_; }                         \
      const float u0_ = __shfl_xor(b0_,2,4), u1_ = __shfl_xor(b1_,2,4);       \
      s_ = (kl & 2) ? (b1_ + u1_) : (b0_ + u0_);                              \
      s_ += __shfl_xor(s_, 4, 16);                                            \
      s_ += __shfl_xor(s_, 8, 16);                                            \
    }                                                                         \
    const float hn_ = fast_tanh(s_ + xpC);                                    \
    if (!last_) {                                                             \
      const u32 tg_ = (u32)(T) + 1u;                                          \
      if (kl < 4) {                                                           \
        *(PL) = hn_;                                                          \
        const u32 bits_ = __float_as_uint(hn_);                               \
        u32x2 pv_;                                                            \
        pv_.x = (tg_<<16) | (bits_>>16);                                      \
        pv_.y = (tg_<<16) | (bits_ & 0xffffu);                                \
        st8_ic((WO), pv_);                                                    \
      }                                                                       \
      if (w < 6) {                                                            \
        u32x2 v_ = ld8_ic(WF); wait_vm0();                                    \
        int guard_ = 1 << 17;                                                 \
        while (!__all((v_.x>>16)==tg_ && (v_.y>>16)==tg_)) {                  \
          if (--guard_ == 0) break;   /* bug => absmax fail, not hang */      \
          v_ = ld8_ic(WF); wait_vm0();                                        \
        }                                                                     \
        *(SD) = __uint_as_float((v_.x<<16) | (v_.y & 0xffffu));               \
      }                                                                       \
      __syncthreads();               /* hS[next par] complete */              \
      xpC = xpN;                                                              \
    }                                                                         \
    hlast = hn_;                                                              \
  }

  for (int t = 0; t < SEQ; t += 2) {
    RSTEP(t,     dA0, pL1, wo1, wf1, sd1);   // even: read par0, write par1
    RSTEP(t + 1, dA1, pL0, wo0, wf0, sd0);   // odd:  read par1, write par0
  }
#undef RSTEP

  if (kl < 4) hfin[(size_t)b*NHID + sj*JSL + jl] = hlast;   // h(2048)
}

// ---------------- fallback (r8, known-pass): batch-split, W row-major -------
__global__ __launch_bounds__(512, 2)
void rnn_seq_fb_kernel(const float* __restrict__ xp,
                       const float* __restrict__ Whh,
                       float* __restrict__ hfin)
{
  const int b = blockIdx.x;
  const int j = threadIdx.x;
  __shared__ __align__(16) float hh[2][NHID];
  hh[0][j] = 0.f;
  const float* wrow = Whh + (size_t)j*NHID;
  const float* xcol = xp + (size_t)b*NHID + j;
  float xpC = xcol[0];
  float hnew = 0.f;
  __syncthreads();
  for (int t = 0; t < SEQ; ++t) {
    const int par = t & 1;
    float xpN = 0.f;
    if (t + 1 < SEQ) xpN = xcol[(size_t)(t+1)*(BATCH*NHID)];
    const float* hA = hh[par];
    float a0=0.f,a1=0.f,a2=0.f,a3=0.f;
    #pragma unroll 8
    for (int kq = 0; kq < 128; ++kq) {
      const float4 wv = *(const float4*)&wrow[kq << 2];
      const float4 hv = *(const float4*)&hA[kq << 2];
      a0 = fmaf(wv.x, hv.x, a0);
      a1 = fmaf(wv.y, hv.y, a1);
      a2 = fmaf(wv.z, hv.z, a2);
      a3 = fmaf(wv.w, hv.w, a3);
    }
    hnew = tanhf((a0+a1)+(a2+a3) + xpC);
    hh[par ^ 1][j] = hnew;
    xpC = xpN;
    __syncthreads();
  }
  hfin[(size_t)b*NHID + j] = hnew;
}

// ---------------- output projection ----------------
__global__ __launch_bounds__(NOUT, 1)
void rnn_out_kernel(const float* __restrict__ hfin,
                    const float* __restrict__ Who,
                    const float* __restrict__ bho,
                    float* __restrict__ out)
{
  const int b = blockIdx.x;
  const int o = threadIdx.x;
  __shared__ __align__(16) float hB[NHID];
  for (int k = o; k < NHID; k += NOUT) hB[k] = hfin[(size_t)b*NHID + k];
  __syncthreads();
  const float* wr = Who + (size_t)o*NHID;
  float a0=0.f,a1=0.f,a2=0.f,a3=0.f;
  for (int k = 0; k < NHID; k += 4) {
    const float4 wv = *(const float4*)&wr[k];
    a0 = fmaf(wv.x, hB[k  ], a0);
    a1 = fmaf(wv.y, hB[k+1], a1);
    a2 = fmaf(wv.z, hB[k+2], a2);
    a3 = fmaf(wv.w, hB[k+3], a3);
  }
  out[(size_t)b*NOUT + o] = (a0+a1)+(a2+a3) + bho[o];
}

extern "C" void kernel_launch(void* const* d_in, const int* in_sizes, int n_in,
                              void* d_out, int out_size, void* d_ws, size_t ws_size,
                              hipStream_t stream)
{
  const float* x   = (const float*)d_in[0];
  const float* Wih = (const float*)d_in[1];
  const float* bih = (const float*)d_in[2];
  const float* Whh = (const float*)d_in[3];
  const float* bhh = (const float*)d_in[4];
  const float* Who = (const float*)d_in[5];
  const float* bho = (const float*)d_in[6];
  float* out = (float*)d_out;

  const size_t need = WIRE_BYTES + HFIN_BYTES + XP_BYTES;

  if (ws_size >= need) {
    u32*   wire = (u32*)d_ws;
    float* hfin = (float*)((char*)d_ws + WIRE_BYTES);
    float* xp   = (float*)((char*)d_ws + WIRE_BYTES + HFIN_BYTES);

    hipMemsetAsync(wire, 0, WIRE_BYTES, stream);   // tags 0; step0 wants tag 1
    xproj_kernel  <<<dim3(2048), dim3(512), 0, stream>>>(x, Wih, bih, bhh, xp);
    rnn_seq4_kernel<<<dim3(NSL*BATCH), dim3(512), 0, stream>>>(xp, Whh, wire, hfin);
    rnn_out_kernel<<<dim3(BATCH), dim3(NOUT), 0, stream>>>(hfin, Who, bho, out);
  } else {
    float* hfin = (float*)d_ws;
    float* xp   = (float*)((char*)d_ws + HFIN_BYTES);
    xproj_kernel<<<dim3(2048), dim3(512), 0, stream>>>(x, Wih, bih, bhh, xp);
    rnn_seq_fb_kernel<<<dim3(BATCH), dim3(512), 0, stream>>>(xp, Whh, hfin);
    rnn_out_kernel<<<dim3(BATCH), dim3(NOUT), 0, stream>>>(hfin, Who, bho, out);
  }
}